// Round 14
// baseline (5043.609 us; speedup 1.0000x reference)
//
#include <hip/hip_runtime.h>
#include <math.h>

// GRUDecoder (NRI decoder) on MI355X — round 14: single-launch recurrence.
// All 39 steps in ONE kernel. Per-batch (16-block) release/acquire barrier
// replaces the launch boundary (~13.5us each). h lives in registers (block-
// local rows). U/V ping-pong swapped in-kernel. W2 fragments + ts hoisted
// once for all steps. Math identical to r13 (absmax 4.394531e-3).
// XCD swizzle keeps each batch's U/V flow inside one XCD's L2.

namespace {
constexpr int kB = 16, kT = 40, kTS = 39, kN = 64, kDin = 64, kH = 256;
constexpr int kE = kN * (kN - 1);   // 4032
constexpr int kBN = kB * kN;        // 1024
constexpr int kDout = 64;
}

typedef _Float16 half8 __attribute__((ext_vector_type(8)));
typedef float f32x4 __attribute__((ext_vector_type(4)));

__device__ __forceinline__ float sigm(float x) { return 1.f / (1.f + expf(-x)); }

__device__ __forceinline__ unsigned short f2h(float x) {
    _Float16 h = (_Float16)x;          // v_cvt_f16_f32, RNE
    return __builtin_bit_cast(unsigned short, h);
}

__device__ __forceinline__ uint4 pack8h(const float* x) {
    unsigned us[8];
    #pragma unroll
    for (int q = 0; q < 8; ++q) us[q] = f2h(x[q]);
    uint4 p;
    p.x = us[0] | (us[1] << 16); p.y = us[2] | (us[3] << 16);
    p.z = us[4] | (us[5] << 16); p.w = us[6] | (us[7] << 16);
    return p;
}

// ---------------- setup: edge table, type sums, all weights -> fp16 ---------
__global__ void setup_kernel(
    const float* __restrict__ rel_rec, const float* __restrict__ rel_send,
    const float* __restrict__ rel_types, const float* __restrict__ W2,
    const float* __restrict__ Whr, const float* __restrict__ Whi,
    const float* __restrict__ Whn, const float* __restrict__ Wir,
    const float* __restrict__ Wii, const float* __restrict__ Win,
    const float* __restrict__ W1,
    const float* __restrict__ bir, const float* __restrict__ bhr,
    const float* __restrict__ bii, const float* __restrict__ bhi,
    const float* __restrict__ fc1w, const float* __restrict__ fc2w,
    const float* __restrict__ fc3w,
    int* __restrict__ edge_at, float* __restrict__ ts,
    unsigned short* __restrict__ W2f,
    unsigned short* __restrict__ Wri,
    unsigned short* __restrict__ Wnh,
    unsigned short* __restrict__ Wnx,
    unsigned short* __restrict__ Wuv,
    unsigned short* __restrict__ F1, unsigned short* __restrict__ F2,
    unsigned short* __restrict__ F3,
    float* __restrict__ bri) {
    int idx = blockIdx.x * 256 + threadIdx.x;
    if (idx < kE) {
        int si = 0, ri = 0;
        for (int n = 0; n < kN; ++n) {
            if (rel_send[idx * kN + n] > 0.5f) si = n;
            if (rel_rec[idx * kN + n] > 0.5f) ri = n;
        }
        edge_at[ri * kN + si] = idx;
    }
    if (idx < kB * kE) ts[idx] = rel_types[2 * idx] + rel_types[2 * idx + 1];
    if (idx < kH * kH) {
        W2f[idx] = f2h(W2[idx]);
        Wnh[idx] = f2h(Whn[idx]);
        F1[idx] = f2h(fc1w[idx]);
        F2[idx] = f2h(fc2w[idx]);
    }
    if (idx < 512 * 320) {  // Wri = [[Whr|Wir],[Whi|Wii]]  rows x K=320
        int row = idx / 320, k = idx - row * 320;
        float v;
        if (row < 256) v = (k < kH) ? Whr[row * kH + k] : Wir[row * kDin + k - kH];
        else { int o = row - 256; v = (k < kH) ? Whi[o * kH + k] : Wii[o * kDin + k - kH]; }
        Wri[idx] = f2h(v);
    }
    if (idx < kH * kDin) Wnx[idx] = f2h(Win[idx]);
    if (idx < 512 * 256) {  // Wuv: row<256 -> U (W1 cols 0..255), else V
        int row = idx >> 8, k = idx & 255;
        float v = (row < 256) ? W1[row * 512 + k] : W1[(row - 256) * 512 + 256 + k];
        Wuv[idx] = f2h(v);
    }
    if (idx < kDout * kH) F3[idx] = f2h(fc3w[idx]);
    if (idx < 256) bri[idx] = bir[idx] + bhr[idx];
    else if (idx < 512) bri[idx] = bii[idx - 256] + bhi[idx - 256];
}

// ---------------- all 39 steps, one launch. 256 blocks x 512 thr ----------
__global__ __launch_bounds__(512, 1)
void step_all_kernel(const float* __restrict__ inputs,
                     float* __restrict__ Ua, float* __restrict__ Va,
                     float* __restrict__ Ub, float* __restrict__ Vb,
                     const unsigned short* __restrict__ W2f,
                     const float* __restrict__ b1, const float* __restrict__ b2,
                     const float* __restrict__ ts, const int* __restrict__ edge_at,
                     const unsigned short* __restrict__ Wri,
                     const unsigned short* __restrict__ Wnh,
                     const unsigned short* __restrict__ Wnx,
                     const unsigned short* __restrict__ Wuv,
                     const float* __restrict__ bri, const float* __restrict__ bhn,
                     const float* __restrict__ bin_,
                     float* __restrict__ hh,
                     unsigned int* __restrict__ bar) {
    __shared__ __align__(16) unsigned short h1[kN * kH];   // 32 KiB, swizzled
    __shared__ float vjb4[4][kH];                          // 4 KiB
    __shared__ float tss4[4][kN];                          // 1 KiB
    __shared__ float aggL[4][kH];                          // 4 KiB
    __shared__ __align__(16) unsigned short Zf[16 * 320];  // 10 KiB
    __shared__ __align__(16) unsigned short Hf[16 * 256];  // 8 KiB

    const int tid = threadIdx.x;
    const int lane = tid & 63, w = tid >> 6;               // 8 waves
    const int mrow = lane & 15, mq = lane >> 4;
    // XCD-chunked swizzle; batch = cb>>4 so blocks of one batch share (bid&7)
    const int cb = ((blockIdx.x & 7) << 5) | (blockIdx.x >> 3);
    const int m0 = cb * 4;
    const int b = cb >> 4, j0 = (cb & 15) * 4;
    const int grp = b;                                     // 16 blocks per group

    // ---- step-invariant preloads
    {
        const int jj = tid >> 7, o = tid & 127;
        if (o < kN) {
            int e = edge_at[(j0 + jj) * kN + o];
            tss4[jj][o] = (e < 0) ? 0.f : ts[b * kE + e];
        }
    }
    const unsigned short* Wp = W2f + (size_t)(w * 32 + mrow) * kH + mq * 8;
    half8 bb[8][2];
    #pragma unroll
    for (int kt = 0; kt < 8; ++kt)
        #pragma unroll
        for (int nf = 0; nf < 2; ++nf)
            bb[kt][nf] = *(const half8*)(Wp + nf * 16 * kH + kt * 32);
    __builtin_amdgcn_sched_barrier(0);
    // zero the constant-zero rows of Zf / Hf once
    {
        const uint4 z4 = {0u, 0u, 0u, 0u};
        for (int c = tid; c < 12 * 40; c += 512) {
            const int r = 4 + c / 40, g = c - (c / 40) * 40;
            *(uint4*)((char*)Zf + r * 640 + ((g ^ (r & 7)) << 4)) = z4;
        }
        for (int c = tid; c < 12 * 32; c += 512) {
            const int r = 4 + c / 32, g = c & 31;
            *(uint4*)((char*)Hf + r * 512 + ((g ^ (r & 7)) << 4)) = z4;
        }
    }

    const int uo = tid & 31, ui0 = tid >> 5;
    float hreg[2][4];                                       // h state, mq==0 lanes
    #pragma unroll
    for (int nf = 0; nf < 2; ++nf)
        #pragma unroll
        for (int r = 0; r < 4; ++r) hreg[nf][r] = 0.f;

    const float* Uc = Ua; const float* Vc = Va;
    float* Un = Ub; float* Vn = Vb;

    #pragma unroll 1
    for (int t = 0; t < kTS; ++t) {
        // ---- per-step: vjb4 from Vc, ur from Uc
        {
            const int jj = tid >> 7, o = tid & 127;
            const int j = j0 + jj;
            vjb4[jj][o] = Vc[(size_t)(b * kN + j) * kH + o] + b1[o];
            vjb4[jj][o + 128] = Vc[(size_t)(b * kN + j) * kH + o + 128] + b1[o + 128];
        }
        float ur[4][8];
        #pragma unroll
        for (int p = 0; p < 4; ++p) {
            const float4* up = (const float4*)(Uc + (size_t)(b * kN + ui0 + 16 * p) * kH + uo * 8);
            *(float4*)&ur[p][0] = up[0];
            *(float4*)&ur[p][4] = up[1];
        }
        __syncthreads();

        // ======== PHASE A: 4 rounds, register->LDS staging ========
        #pragma unroll 1
        for (int jj = 0; jj < 4; ++jj) {
            const int j = j0 + jj;
            {
                const int k0 = uo * 8;
                float vj[8];
                *(float4*)&vj[0] = *(const float4*)&vjb4[jj][k0];
                *(float4*)&vj[4] = *(const float4*)&vjb4[jj][k0 + 4];
                #pragma unroll
                for (int p = 0; p < 4; ++p) {
                    const int i = ui0 + 16 * p;
                    float x[8];
                    #pragma unroll
                    for (int q = 0; q < 8; ++q)
                        x[q] = (i == j) ? 0.f : fmaxf(ur[p][q] + vj[q], 0.f);
                    *(uint4*)((char*)h1 + i * 512 + ((k0 * 2) ^ ((i & 7) << 4))) = pack8h(x);
                }
            }
            __syncthreads();

            f32x4 acc[4][2];
            #pragma unroll
            for (int mf = 0; mf < 4; ++mf)
                #pragma unroll
                for (int nf = 0; nf < 2; ++nf) acc[mf][nf] = (f32x4){0.f, 0.f, 0.f, 0.f};
            #pragma unroll
            for (int kt = 0; kt < 8; ++kt) {
                const int k0 = kt * 32;
                half8 a[4];
                #pragma unroll
                for (int mf = 0; mf < 4; ++mf) {
                    const int r = mf * 16 + mrow;
                    a[mf] = *(const half8*)((const char*)h1 + r * 512 +
                                            (((k0 + mq * 8) * 2) ^ ((r & 7) << 4)));
                }
                #pragma unroll
                for (int mf = 0; mf < 4; ++mf)
                    #pragma unroll
                    for (int nf = 0; nf < 2; ++nf)
                        acc[mf][nf] = __builtin_amdgcn_mfma_f32_16x16x32_f16(
                            a[mf], bb[kt][nf], acc[mf][nf], 0, 0, 0);
            }

            float tsr[16];
            #pragma unroll
            for (int mf = 0; mf < 4; ++mf)
                #pragma unroll
                for (int r = 0; r < 4; ++r)
                    tsr[mf * 4 + r] = tss4[jj][mf * 16 + mq * 4 + r];
            #pragma unroll
            for (int nf = 0; nf < 2; ++nf) {
                const int col = w * 32 + nf * 16 + mrow;
                const float bv = b2[col];
                float s = 0.f;
                #pragma unroll
                for (int mf = 0; mf < 4; ++mf)
                    #pragma unroll
                    for (int r = 0; r < 4; ++r)
                        s += tsr[mf * 4 + r] * fmaxf(acc[mf][nf][r] + bv, 0.f);
                s += __shfl_xor(s, 16);
                s += __shfl_xor(s, 32);
                if (lane < 16) aggL[jj][col] = s;
            }
            __syncthreads();
        }

        // ======== PHASE B ========
        for (int c = tid; c < 4 * 40; c += 512) {
            const int r = c / 40, g = c - r * 40;
            float x[8];
            if (g < 32) {
                #pragma unroll
                for (int q = 0; q < 8; ++q) x[q] = aggL[r][g * 8 + q];
            } else {
                const int grow = m0 + r, bb_ = grow >> 6, n = grow & 63;
                const float* xp = inputs + ((size_t)(bb_ * kT + t) * kN + n) * kDin + (g - 32) * 8;
                *(float4*)&x[0] = ((const float4*)xp)[0];
                *(float4*)&x[4] = ((const float4*)xp)[1];
            }
            *(uint4*)((char*)Zf + r * 640 + ((g ^ (r & 7)) << 4)) = pack8h(x);
        }
        __syncthreads();

        // GEMM1: 2 nf per wave
        #pragma unroll
        for (int nf = 0; nf < 2; ++nf) {
            const int col = w * 32 + nf * 16 + mrow;
            const unsigned short* WR = Wri + (size_t)col * 320 + mq * 8;
            const unsigned short* WI = Wri + (size_t)(256 + col) * 320 + mq * 8;
            const unsigned short* WNh = Wnh + (size_t)col * kH + mq * 8;
            const unsigned short* WNx = Wnx + (size_t)col * kDin + mq * 8;

            half8 rwa[10][3];
            #pragma unroll
            for (int kt = 0; kt < 10; ++kt) {
                rwa[kt][0] = *(const half8*)(WR + kt * 32);
                rwa[kt][1] = *(const half8*)(WI + kt * 32);
                if (kt < 8) rwa[kt][2] = *(const half8*)(WNh + kt * 32);
                else        rwa[kt][2] = *(const half8*)(WNx + (kt * 32 - 256));
            }
            __builtin_amdgcn_sched_barrier(0);

            f32x4 aR = {0.f,0.f,0.f,0.f}, aI = {0.f,0.f,0.f,0.f};
            f32x4 aNH = {0.f,0.f,0.f,0.f}, aNX = {0.f,0.f,0.f,0.f};
            #pragma unroll
            for (int kt = 0; kt < 10; ++kt) {
                const int g = kt * 4 + mq;
                half8 zf = *(const half8*)((const char*)Zf + mrow * 640 + ((g ^ (mrow & 7)) << 4));
                aR = __builtin_amdgcn_mfma_f32_16x16x32_f16(zf, rwa[kt][0], aR, 0, 0, 0);
                aI = __builtin_amdgcn_mfma_f32_16x16x32_f16(zf, rwa[kt][1], aI, 0, 0, 0);
                if (kt < 8) aNH = __builtin_amdgcn_mfma_f32_16x16x32_f16(zf, rwa[kt][2], aNH, 0, 0, 0);
                else        aNX = __builtin_amdgcn_mfma_f32_16x16x32_f16(zf, rwa[kt][2], aNX, 0, 0, 0);
            }

            if (mq == 0) {
                const float brv = bri[col], biv = bri[256 + col];
                const float bhnv = bhn[col], binv = bin_[col];
                #pragma unroll
                for (int reg = 0; reg < 4; ++reg) {
                    const int grow = m0 + reg;
                    float rg = sigm(aR[reg] + brv);
                    float ig = sigm(aI[reg] + biv);
                    float ng = tanhf(aNX[reg] + binv + rg * (aNH[reg] + bhnv));
                    float h2 = (1.f - ig) * ng + ig * hreg[nf][reg];
                    hreg[nf][reg] = h2;
                    hh[((size_t)(t + 1) * kBN + grow) * kH + col] = h2;
                    *(unsigned short*)((char*)Hf + reg * 512 +
                        (((col >> 3) ^ (reg & 7)) << 4) + (col & 7) * 2) = f2h(h2);
                }
            }
        }
        __syncthreads();

        // GEMM2: 4 nf per wave -> Un, Vn
        #pragma unroll
        for (int nf = 0; nf < 4; ++nf) {
            const int col = w * 64 + nf * 16 + mrow;
            const unsigned short* Wp2 = Wuv + (size_t)col * kH + mq * 8;
            half8 rwa[8];
            #pragma unroll
            for (int kt = 0; kt < 8; ++kt) rwa[kt] = *(const half8*)(Wp2 + kt * 32);
            __builtin_amdgcn_sched_barrier(0);
            f32x4 aUV = {0.f, 0.f, 0.f, 0.f};
            #pragma unroll
            for (int kt = 0; kt < 8; ++kt) {
                const int g = kt * 4 + mq;
                half8 zf = *(const half8*)((const char*)Hf + mrow * 512 + ((g ^ (mrow & 7)) << 4));
                aUV = __builtin_amdgcn_mfma_f32_16x16x32_f16(zf, rwa[kt], aUV, 0, 0, 0);
            }
            if (mq == 0) {
                #pragma unroll
                for (int reg = 0; reg < 4; ++reg) {
                    const int grow = m0 + reg;
                    const float v = aUV[reg];
                    if (col < 256) Un[(size_t)grow * kH + col] = v;
                    else Vn[(size_t)grow * kH + col - 256] = v;
                }
            }
        }

        // ---- per-batch barrier (release writes, acquire before next read)
        if (t + 1 < kTS) {
            __threadfence();
            __syncthreads();
            if (tid == 0)
                __hip_atomic_fetch_add(&bar[grp], 1u, __ATOMIC_RELEASE,
                                       __HIP_MEMORY_SCOPE_AGENT);
            const unsigned target = 16u * (unsigned)(t + 1);
            if (tid == 0) {
                while (__hip_atomic_load(&bar[grp], __ATOMIC_ACQUIRE,
                                         __HIP_MEMORY_SCOPE_AGENT) < target)
                    __builtin_amdgcn_s_sleep(2);
            }
            __syncthreads();
            __threadfence();
            // swap ping-pong
            const float* tU = Uc; Uc = Un; Un = (float*)tU;
            const float* tV = Vc; Vc = Vn; Vn = (float*)tV;
        }
    }
}

// ---------------- batched output MLP (fp16 MFMA), 64 rows/block -------------
__global__ __launch_bounds__(256, 2)
void out_kernel(const float* __restrict__ hist,
                const unsigned short* __restrict__ F1,
                const unsigned short* __restrict__ F2,
                const unsigned short* __restrict__ F3,
                const float* __restrict__ fc1b, const float* __restrict__ fc2b,
                const float* __restrict__ fc3b, float* __restrict__ out) {
    __shared__ __align__(16) unsigned short Af[64 * 256];  // 32 KiB
    __shared__ __align__(16) unsigned short Bf[64 * 256];  // 32 KiB
    const int m0 = blockIdx.x * 64;
    const int tid = threadIdx.x;
    const int lane = tid & 63, w = tid >> 6;
    const int mrow = lane & 15, mq = lane >> 4;

    #pragma unroll
    for (int it = 0; it < 8; ++it) {
        const int c = tid + it * 256;
        const int r = c >> 5, o = c & 31;
        const float* ap = hist + (size_t)(m0 + r) * kH + o * 8;
        float x[8];
        *(float4*)&x[0] = ((const float4*)ap)[0];
        *(float4*)&x[4] = ((const float4*)ap)[1];
        const int byte = r * 512 + ((o << 4) ^ ((r & 7) << 4));
        *(uint4*)((char*)Af + byte) = pack8h(x);
    }
    __syncthreads();

    #define LAYER(SRC, WW, BIAS, DST)                                           \
    {                                                                           \
        const unsigned short* wb = WW + (size_t)(w * 64 + mrow) * kH + mq * 8;  \
        half8 wall[8][4];                                                       \
        _Pragma("unroll")                                                       \
        for (int kt = 0; kt < 8; ++kt)                                          \
            _Pragma("unroll")                                                   \
            for (int nf = 0; nf < 4; ++nf)                                      \
                wall[kt][nf] = *(const half8*)(wb + nf * 16 * kH + kt * 32);    \
        __builtin_amdgcn_sched_barrier(0);                                      \
        f32x4 acc[4][4];                                                        \
        _Pragma("unroll")                                                       \
        for (int m = 0; m < 4; ++m)                                             \
            _Pragma("unroll")                                                   \
            for (int nf = 0; nf < 4; ++nf) acc[m][nf] = (f32x4){0.f,0.f,0.f,0.f};\
        _Pragma("unroll")                                                       \
        for (int kt = 0; kt < 8; ++kt) {                                        \
            const int k0 = kt * 32;                                             \
            half8 zf[4];                                                        \
            _Pragma("unroll")                                                   \
            for (int m = 0; m < 4; ++m) {                                       \
                const int r = m * 16 + mrow;                                    \
                const int byte = r * 512 + (((k0 + mq * 8) * 2) ^ ((r & 7) << 4)); \
                zf[m] = *(const half8*)((const char*)SRC + byte);               \
            }                                                                   \
            _Pragma("unroll")                                                   \
            for (int m = 0; m < 4; ++m)                                         \
                _Pragma("unroll")                                               \
                for (int nf = 0; nf < 4; ++nf)                                  \
                    acc[m][nf] = __builtin_amdgcn_mfma_f32_16x16x32_f16(        \
                        zf[m], wall[kt][nf], acc[m][nf], 0, 0, 0);              \
        }                                                                       \
        _Pragma("unroll")                                                       \
        for (int m = 0; m < 4; ++m)                                             \
            _Pragma("unroll")                                                   \
            for (int nf = 0; nf < 4; ++nf) {                                    \
                const int col = w * 64 + nf * 16 + mrow;                        \
                const float bv = BIAS[col];                                     \
                _Pragma("unroll")                                               \
                for (int reg = 0; reg < 4; ++reg) {                             \
                    const int lr = m * 16 + mq * 4 + reg;                       \
                    float v = fmaxf(acc[m][nf][reg] + bv, 0.f);                 \
                    const int byte = lr * 512 + (((col >> 3) ^ (lr & 7)) << 4) + (col & 7) * 2; \
                    *(unsigned short*)((char*)DST + byte) = f2h(v);             \
                }                                                               \
            }                                                                   \
        __syncthreads();                                                        \
    }

    LAYER(Af, F1, fc1b, Bf)
    LAYER(Bf, F2, fc2b, Af)

    {
        const int row = w * 16 + mrow;
        const unsigned short* wb = F3 + (size_t)row * kH + mq * 8;
        half8 wall[8];
        #pragma unroll
        for (int kt = 0; kt < 8; ++kt) wall[kt] = *(const half8*)(wb + kt * 32);
        __builtin_amdgcn_sched_barrier(0);
        f32x4 acc[4];
        #pragma unroll
        for (int m = 0; m < 4; ++m) acc[m] = (f32x4){0.f, 0.f, 0.f, 0.f};
        #pragma unroll
        for (int kt = 0; kt < 8; ++kt) {
            const int k0 = kt * 32;
            half8 zf[4];
            #pragma unroll
            for (int m = 0; m < 4; ++m) {
                const int r = m * 16 + mrow;
                const int byte = r * 512 + (((k0 + mq * 8) * 2) ^ ((r & 7) << 4));
                zf[m] = *(const half8*)((const char*)Af + byte);
            }
            #pragma unroll
            for (int m = 0; m < 4; ++m)
                acc[m] = __builtin_amdgcn_mfma_f32_16x16x32_f16(zf[m], wall[kt], acc[m], 0, 0, 0);
        }
        const int col = w * 16 + mrow;
        const float bv = fc3b[col];
        #pragma unroll
        for (int m = 0; m < 4; ++m)
            #pragma unroll
            for (int reg = 0; reg < 4; ++reg) {
                const int grow = m0 + m * 16 + mq * 4 + reg;
                const int t = grow >> 10, bn = grow & 1023, b = bn >> 6, n = bn & 63;
                out[(((size_t)b * kTS + t) * kN + n) * kDout + col] = acc[m][reg] + bv;
            }
    }
    #undef LAYER
}

extern "C" void kernel_launch(void* const* d_in, const int* in_sizes, int n_in,
                              void* d_out, int out_size, void* d_ws, size_t ws_size,
                              hipStream_t stream) {
    const float* inputs    = (const float*)d_in[0];
    const float* rel_rec   = (const float*)d_in[1];
    const float* rel_send  = (const float*)d_in[2];
    const float* rel_types = (const float*)d_in[3];
    const float* W1  = (const float*)d_in[4];  const float* b1  = (const float*)d_in[5];
    const float* W2  = (const float*)d_in[6];  const float* b2  = (const float*)d_in[7];
    const float* Wir = (const float*)d_in[8];  const float* bir = (const float*)d_in[9];
    const float* Whr = (const float*)d_in[10]; const float* bhr = (const float*)d_in[11];
    const float* Wii = (const float*)d_in[12]; const float* bii = (const float*)d_in[13];
    const float* Whi = (const float*)d_in[14]; const float* bhi = (const float*)d_in[15];
    const float* Win = (const float*)d_in[16]; const float* bin_ = (const float*)d_in[17];
    const float* Whn = (const float*)d_in[18]; const float* bhn = (const float*)d_in[19];
    const float* fc1w = (const float*)d_in[20]; const float* fc1b = (const float*)d_in[21];
    const float* fc2w = (const float*)d_in[22]; const float* fc2b = (const float*)d_in[23];
    const float* fc3w = (const float*)d_in[24]; const float* fc3b = (const float*)d_in[25];
    float* out = (float*)d_out;

    char* w = (char*)d_ws;
    auto take = [&](size_t bytes) { char* p = w; w += (bytes + 255) & ~(size_t)255; return p; };
    int* edge_at = (int*)take(kN * kN * 4);
    float* ts = (float*)take(kB * kE * 4);
    unsigned short* W2f = (unsigned short*)take(kH * kH * 2);
    unsigned short* Wri = (unsigned short*)take(512 * 320 * 2);
    unsigned short* Wnh = (unsigned short*)take(kH * kH * 2);
    unsigned short* Wnx = (unsigned short*)take(kH * kDin * 2);
    unsigned short* Wuv = (unsigned short*)take(512 * 256 * 2);
    unsigned short* F1 = (unsigned short*)take(kH * kH * 2);
    unsigned short* F2 = (unsigned short*)take(kH * kH * 2);
    unsigned short* F3 = (unsigned short*)take(kDout * kH * 2);
    float* bri = (float*)take(512 * 4);
    unsigned int* bar = (unsigned int*)take(kB * 4);
    float* Ua = (float*)take((size_t)kBN * kH * 4);
    float* Va = (float*)take((size_t)kBN * kH * 4);
    float* Ub = (float*)take((size_t)kBN * kH * 4);
    float* Vb = (float*)take((size_t)kBN * kH * 4);
    float* hh = (float*)w;   // (kTS+1) * kBN * kH floats (~42 MiB)

    hipMemsetAsync(edge_at, 0xFF, kN * kN * 4, stream);
    hipMemsetAsync(bar, 0, kB * 4, stream);
    setup_kernel<<<640, 256, 0, stream>>>(
        rel_rec, rel_send, rel_types, W2, Whr, Whi, Whn, Wir, Wii, Win, W1,
        bir, bhr, bii, bhi, fc1w, fc2w, fc3w,
        edge_at, ts, W2f, Wri, Wnh, Wnx, Wuv, F1, F2, F3, bri);
    hipMemsetAsync(Ua, 0, (size_t)kBN * kH * 4, stream);
    hipMemsetAsync(Va, 0, (size_t)kBN * kH * 4, stream);

    step_all_kernel<<<256, 512, 0, stream>>>(
        inputs, Ua, Va, Ub, Vb, W2f, b1, b2, ts, edge_at,
        Wri, Wnh, Wnx, Wuv, bri, bhn, bin_, hh, bar);

    out_kernel<<<kTS * kBN / 64, 256, 0, stream>>>(
        hh + (size_t)kBN * kH, F1, F2, F3, fc1b, fc2b, fc3b, out);
}

// Round 15
// 1553.718 us; speedup vs baseline: 3.2462x; 3.2462x over previous
//
#include <hip/hip_runtime.h>
#include <math.h>

// GRUDecoder (NRI decoder) on MI355X — round 15.
// = r13 (best, 1560us) + isolated fp16 hidden-history:
//  - step_kernel nontemporal-stores f2h(h2) (already computed) to hist16;
//    fp32 recurrence h in 2 ping-pong buffers (bit-identical math)
//  - out_kernel reads hist16 directly (it converted to fp16 anyway ->
//    output bit-identical; halves its HBM fetch)
// r14 (in-kernel barrier) reverted: device fences invalidated L2/L3 ->
// 3.5 GB/dispatch HBM refetch. Launch boundary is the cheap sync primitive.

namespace {
constexpr int kB = 16, kT = 40, kTS = 39, kN = 64, kDin = 64, kH = 256;
constexpr int kE = kN * (kN - 1);   // 4032
constexpr int kBN = kB * kN;        // 1024
constexpr int kDout = 64;
}

typedef _Float16 half8 __attribute__((ext_vector_type(8)));
typedef short short8 __attribute__((ext_vector_type(8)));
typedef float f32x4 __attribute__((ext_vector_type(4)));

__device__ __forceinline__ float sigm(float x) { return 1.f / (1.f + expf(-x)); }

__device__ __forceinline__ unsigned short f2h(float x) {
    _Float16 h = (_Float16)x;          // v_cvt_f16_f32, RNE
    return __builtin_bit_cast(unsigned short, h);
}

__device__ __forceinline__ uint4 pack8h(const float* x) {
    unsigned us[8];
    #pragma unroll
    for (int q = 0; q < 8; ++q) us[q] = f2h(x[q]);
    uint4 p;
    p.x = us[0] | (us[1] << 16); p.y = us[2] | (us[3] << 16);
    p.z = us[4] | (us[5] << 16); p.w = us[6] | (us[7] << 16);
    return p;
}

// ---------------- setup: edge table, type sums, all weights -> fp16 ---------
__global__ void setup_kernel(
    const float* __restrict__ rel_rec, const float* __restrict__ rel_send,
    const float* __restrict__ rel_types, const float* __restrict__ W2,
    const float* __restrict__ Whr, const float* __restrict__ Whi,
    const float* __restrict__ Whn, const float* __restrict__ Wir,
    const float* __restrict__ Wii, const float* __restrict__ Win,
    const float* __restrict__ W1,
    const float* __restrict__ bir, const float* __restrict__ bhr,
    const float* __restrict__ bii, const float* __restrict__ bhi,
    const float* __restrict__ fc1w, const float* __restrict__ fc2w,
    const float* __restrict__ fc3w,
    int* __restrict__ edge_at, float* __restrict__ ts,
    unsigned short* __restrict__ W2f,
    unsigned short* __restrict__ Wri,
    unsigned short* __restrict__ Wnh,
    unsigned short* __restrict__ Wnx,
    unsigned short* __restrict__ Wuv,
    unsigned short* __restrict__ F1, unsigned short* __restrict__ F2,
    unsigned short* __restrict__ F3,
    float* __restrict__ bri) {
    int idx = blockIdx.x * 256 + threadIdx.x;
    if (idx < kE) {
        int si = 0, ri = 0;
        for (int n = 0; n < kN; ++n) {
            if (rel_send[idx * kN + n] > 0.5f) si = n;
            if (rel_rec[idx * kN + n] > 0.5f) ri = n;
        }
        edge_at[ri * kN + si] = idx;
    }
    if (idx < kB * kE) ts[idx] = rel_types[2 * idx] + rel_types[2 * idx + 1];
    if (idx < kH * kH) {
        W2f[idx] = f2h(W2[idx]);
        Wnh[idx] = f2h(Whn[idx]);
        F1[idx] = f2h(fc1w[idx]);
        F2[idx] = f2h(fc2w[idx]);
    }
    if (idx < 512 * 320) {  // Wri = [[Whr|Wir],[Whi|Wii]]  rows x K=320
        int row = idx / 320, k = idx - row * 320;
        float v;
        if (row < 256) v = (k < kH) ? Whr[row * kH + k] : Wir[row * kDin + k - kH];
        else { int o = row - 256; v = (k < kH) ? Whi[o * kH + k] : Wii[o * kDin + k - kH]; }
        Wri[idx] = f2h(v);
    }
    if (idx < kH * kDin) Wnx[idx] = f2h(Win[idx]);
    if (idx < 512 * 256) {  // Wuv: row<256 -> U (W1 cols 0..255), else V
        int row = idx >> 8, k = idx & 255;
        float v = (row < 256) ? W1[row * 512 + k] : W1[(row - 256) * 512 + 256 + k];
        Wuv[idx] = f2h(v);
    }
    if (idx < kDout * kH) F3[idx] = f2h(fc3w[idx]);
    if (idx < 256) bri[idx] = bir[idx] + bhr[idx];
    else if (idx < 512) bri[idx] = bii[idx - 256] + bhi[idx - 256];
}

// ---------------- per-step fused kernel: edge (4 receivers) + their GRU ----
// 256 blocks x 512 thr (8 waves, 1 block/CU). XCD-chunked swizzle: cb.
__global__ __launch_bounds__(512, 1)
void step_kernel(const float* __restrict__ hprev,
                 const float* __restrict__ inputs, int t,
                 const float* __restrict__ Uin, const float* __restrict__ Vin,
                 const unsigned short* __restrict__ W2f,
                 const float* __restrict__ b1, const float* __restrict__ b2,
                 const float* __restrict__ ts, const int* __restrict__ edge_at,
                 const unsigned short* __restrict__ Wri,
                 const unsigned short* __restrict__ Wnh,
                 const unsigned short* __restrict__ Wnx,
                 const unsigned short* __restrict__ Wuv,
                 const float* __restrict__ bri, const float* __restrict__ bhn,
                 const float* __restrict__ bin_,
                 float* __restrict__ hnew,
                 float* __restrict__ Uo, float* __restrict__ Vo,
                 unsigned short* __restrict__ hist16) {
    __shared__ __align__(16) unsigned short h1[kN * kH];   // 32 KiB, swizzled
    __shared__ float vjb4[4][kH];                          // 4 KiB
    __shared__ float tss4[4][kN];                          // 1 KiB
    __shared__ float aggL[4][kH];                          // 4 KiB
    __shared__ __align__(16) unsigned short Zf[16 * 320];  // 10 KiB
    __shared__ __align__(16) unsigned short Hf[16 * 256];  // 8 KiB

    const int tid = threadIdx.x;
    const int lane = tid & 63, w = tid >> 6;               // 8 waves
    const int mrow = lane & 15, mq = lane >> 4;
    // XCD-chunked swizzle (round-robin bid->XCD assumed: bid%8). Bijective for
    // 256 blocks. Performance heuristic only (correctness launch-ordered).
    const int cb = ((blockIdx.x & 7) << 5) | (blockIdx.x >> 3);
    const int m0 = cb * 4;                                 // global rows
    const int b = cb >> 4, j0 = (cb & 15) * 4;

    // ---- preload V_j + b1 and ts for all 4 receivers (single global pass)
    {
        const int jj = tid >> 7, o = tid & 127;            // 4 x 128 threads
        const int j = j0 + jj;
        vjb4[jj][o] = Vin[(size_t)(b * kN + j) * kH + o] + b1[o];
        vjb4[jj][o + 128] = Vin[(size_t)(b * kN + j) * kH + o + 128] + b1[o + 128];
        if (o < kN) {
            int e = edge_at[j * kN + o];
            tss4[jj][o] = (e < 0) ? 0.f : ts[b * kE + e];
        }
    }

    // ---- load the receiver-invariant U tile ONCE into registers
    const int uo = tid & 31, ui0 = tid >> 5;
    float ur[4][8];
    #pragma unroll
    for (int p = 0; p < 4; ++p) {
        const float4* up = (const float4*)(Uin + (size_t)(b * kN + ui0 + 16 * p) * kH + uo * 8);
        *(float4*)&ur[p][0] = up[0];
        *(float4*)&ur[p][4] = up[1];
    }

    // ---- hoist W2 fragments for this wave's 32 cols (16 x 16B = 64 VGPR)
    const unsigned short* Wp = W2f + (size_t)(w * 32 + mrow) * kH + mq * 8;
    half8 bb[8][2];
    #pragma unroll
    for (int kt = 0; kt < 8; ++kt)
        #pragma unroll
        for (int nf = 0; nf < 2; ++nf)
            bb[kt][nf] = *(const half8*)(Wp + nf * 16 * kH + kt * 32);
    __builtin_amdgcn_sched_barrier(0);
    __syncthreads();

    // ======== PHASE A: 4 rounds, staging is register->LDS (no global) ========
    #pragma unroll 1
    for (int jj = 0; jj < 4; ++jj) {
        const int j = j0 + jj;
        // stage h1 = relu(ur + vjb4[jj]) as fp16, swizzle byte ^= (row&7)<<4
        {
            const int k0 = uo * 8;
            float vj[8];
            *(float4*)&vj[0] = *(const float4*)&vjb4[jj][k0];
            *(float4*)&vj[4] = *(const float4*)&vjb4[jj][k0 + 4];
            #pragma unroll
            for (int p = 0; p < 4; ++p) {
                const int i = ui0 + 16 * p;
                float x[8];
                #pragma unroll
                for (int q = 0; q < 8; ++q)
                    x[q] = (i == j) ? 0.f : fmaxf(ur[p][q] + vj[q], 0.f);
                const int byte = i * 512 + ((k0 * 2) ^ ((i & 7) << 4));
                *(uint4*)((char*)h1 + byte) = pack8h(x);
            }
        }
        __syncthreads();

        // MFMA: wave w -> cols [w*32, w*32+32), full M=64
        f32x4 acc[4][2];
        #pragma unroll
        for (int mf = 0; mf < 4; ++mf)
            #pragma unroll
            for (int nf = 0; nf < 2; ++nf) acc[mf][nf] = (f32x4){0.f, 0.f, 0.f, 0.f};
        #pragma unroll
        for (int kt = 0; kt < 8; ++kt) {
            const int k0 = kt * 32;
            half8 a[4];
            #pragma unroll
            for (int mf = 0; mf < 4; ++mf) {
                const int r = mf * 16 + mrow;
                const int byte = r * 512 + (((k0 + mq * 8) * 2) ^ ((r & 7) << 4));
                a[mf] = *(const half8*)((const char*)h1 + byte);
            }
            #pragma unroll
            for (int mf = 0; mf < 4; ++mf)
                #pragma unroll
                for (int nf = 0; nf < 2; ++nf)
                    acc[mf][nf] = __builtin_amdgcn_mfma_f32_16x16x32_f16(
                        a[mf], bb[kt][nf], acc[mf][nf], 0, 0, 0);
        }

        // epilogue: relu(+b2), ts-weight, reduce over senders -> aggL[jj]
        float tsr[16];
        #pragma unroll
        for (int mf = 0; mf < 4; ++mf)
            #pragma unroll
            for (int r = 0; r < 4; ++r)
                tsr[mf * 4 + r] = tss4[jj][mf * 16 + mq * 4 + r];
        #pragma unroll
        for (int nf = 0; nf < 2; ++nf) {
            const int col = w * 32 + nf * 16 + mrow;
            const float bv = b2[col];
            float s = 0.f;
            #pragma unroll
            for (int mf = 0; mf < 4; ++mf)
                #pragma unroll
                for (int r = 0; r < 4; ++r)
                    s += tsr[mf * 4 + r] * fmaxf(acc[mf][nf][r] + bv, 0.f);
            s += __shfl_xor(s, 16);
            s += __shfl_xor(s, 32);
            if (lane < 16) aggL[jj][col] = s;
        }
        __syncthreads();   // aggL done; safe to restage h1 next round
    }

    // ======== PHASE B: GRU gates + hnew + U,V for rows m0..m0+3 ========
    {
        const uint4 z4 = {0u, 0u, 0u, 0u};
        for (int c = tid; c < 4 * 40; c += 512) {
            const int r = c / 40, g = c - r * 40;
            float x[8];
            if (g < 32) {
                #pragma unroll
                for (int q = 0; q < 8; ++q) x[q] = aggL[r][g * 8 + q];
            } else {
                const int grow = m0 + r, bb_ = grow >> 6, n = grow & 63;
                const float* xp = inputs + ((size_t)(bb_ * kT + t) * kN + n) * kDin + (g - 32) * 8;
                *(float4*)&x[0] = ((const float4*)xp)[0];
                *(float4*)&x[4] = ((const float4*)xp)[1];
            }
            const int byte = r * 640 + ((g ^ (r & 7)) << 4);
            *(uint4*)((char*)Zf + byte) = pack8h(x);
        }
        for (int c = tid; c < 12 * 40; c += 512) {
            const int r = 4 + c / 40, g = c - (c / 40) * 40;
            const int byte = r * 640 + ((g ^ (r & 7)) << 4);
            *(uint4*)((char*)Zf + byte) = z4;
        }
        for (int c = tid; c < 12 * 32; c += 512) {
            const int r = 4 + c / 32, g = c & 31;
            const int byte = r * 512 + ((g ^ (r & 7)) << 4);
            *(uint4*)((char*)Hf + byte) = z4;
        }
    }
    __syncthreads();

    // GEMM1: 2 nf per wave (8 waves x 32 cols = 256)
    #pragma unroll
    for (int nf = 0; nf < 2; ++nf) {
        const int col = w * 32 + nf * 16 + mrow;
        const unsigned short* WR = Wri + (size_t)col * 320 + mq * 8;
        const unsigned short* WI = Wri + (size_t)(256 + col) * 320 + mq * 8;
        const unsigned short* WNh = Wnh + (size_t)col * kH + mq * 8;
        const unsigned short* WNx = Wnx + (size_t)col * kDin + mq * 8;

        half8 rwa[10][3];
        #pragma unroll
        for (int kt = 0; kt < 10; ++kt) {
            rwa[kt][0] = *(const half8*)(WR + kt * 32);
            rwa[kt][1] = *(const half8*)(WI + kt * 32);
            if (kt < 8) rwa[kt][2] = *(const half8*)(WNh + kt * 32);
            else        rwa[kt][2] = *(const half8*)(WNx + (kt * 32 - 256));
        }
        __builtin_amdgcn_sched_barrier(0);

        f32x4 aR = {0.f,0.f,0.f,0.f}, aI = {0.f,0.f,0.f,0.f};
        f32x4 aNH = {0.f,0.f,0.f,0.f}, aNX = {0.f,0.f,0.f,0.f};
        #pragma unroll
        for (int kt = 0; kt < 10; ++kt) {
            const int g = kt * 4 + mq;
            const int byte = mrow * 640 + ((g ^ (mrow & 7)) << 4);
            half8 zf = *(const half8*)((const char*)Zf + byte);
            aR = __builtin_amdgcn_mfma_f32_16x16x32_f16(zf, rwa[kt][0], aR, 0, 0, 0);
            aI = __builtin_amdgcn_mfma_f32_16x16x32_f16(zf, rwa[kt][1], aI, 0, 0, 0);
            if (kt < 8) aNH = __builtin_amdgcn_mfma_f32_16x16x32_f16(zf, rwa[kt][2], aNH, 0, 0, 0);
            else        aNX = __builtin_amdgcn_mfma_f32_16x16x32_f16(zf, rwa[kt][2], aNX, 0, 0, 0);
        }

        if (mq == 0) {  // D rows 0..3 are the real rows
            const float brv = bri[col], biv = bri[256 + col];
            const float bhnv = bhn[col], binv = bin_[col];
            #pragma unroll
            for (int reg = 0; reg < 4; ++reg) {
                const int lr = reg;
                const int grow = m0 + lr;
                float rg = sigm(aR[reg] + brv);
                float ig = sigm(aI[reg] + biv);
                float ng = tanhf(aNX[reg] + binv + rg * (aNH[reg] + bhnv));
                float h2 = (1.f - ig) * ng + ig * hprev[(size_t)grow * kH + col];
                hnew[(size_t)grow * kH + col] = h2;
                const unsigned short hv = f2h(h2);
                // nontemporal: stream to HBM without polluting L2 (r11 lesson)
                __builtin_nontemporal_store(
                    hv, &hist16[((size_t)t * kBN + grow) * kH + col]);
                const int byte = lr * 512 + (((col >> 3) ^ (lr & 7)) << 4) + (col & 7) * 2;
                *(unsigned short*)((char*)Hf + byte) = hv;
            }
        }
    }
    __syncthreads();

    // GEMM2: 4 nf per wave (8 waves x 64 cols = 512) -> U,V
    #pragma unroll
    for (int nf = 0; nf < 4; ++nf) {
        const int col = w * 64 + nf * 16 + mrow;
        const unsigned short* Wp2 = Wuv + (size_t)col * kH + mq * 8;
        half8 rwa[8];
        #pragma unroll
        for (int kt = 0; kt < 8; ++kt) rwa[kt] = *(const half8*)(Wp2 + kt * 32);
        __builtin_amdgcn_sched_barrier(0);
        f32x4 aUV = {0.f, 0.f, 0.f, 0.f};
        #pragma unroll
        for (int kt = 0; kt < 8; ++kt) {
            const int g = kt * 4 + mq;
            const int byte = mrow * 512 + ((g ^ (mrow & 7)) << 4);
            half8 zf = *(const half8*)((const char*)Hf + byte);
            aUV = __builtin_amdgcn_mfma_f32_16x16x32_f16(zf, rwa[kt], aUV, 0, 0, 0);
        }
        if (mq == 0) {
            #pragma unroll
            for (int reg = 0; reg < 4; ++reg) {
                const int grow = m0 + reg;
                const float v = aUV[reg];
                if (col < 256) Uo[(size_t)grow * kH + col] = v;
                else Vo[(size_t)grow * kH + col - 256] = v;
            }
        }
    }
}

// ---------------- batched output MLP (fp16 MFMA), fp16 history input --------
__global__ __launch_bounds__(256, 2)
void out_kernel(const unsigned short* __restrict__ hist16,
                const unsigned short* __restrict__ F1,
                const unsigned short* __restrict__ F2,
                const unsigned short* __restrict__ F3,
                const float* __restrict__ fc1b, const float* __restrict__ fc2b,
                const float* __restrict__ fc3b, float* __restrict__ out) {
    __shared__ __align__(16) unsigned short Af[64 * 256];  // 32 KiB
    __shared__ __align__(16) unsigned short Bf[64 * 256];  // 32 KiB
    const int m0 = blockIdx.x * 64;
    const int tid = threadIdx.x;
    const int lane = tid & 63, w = tid >> 6;
    const int mrow = lane & 15, mq = lane >> 4;

    #pragma unroll
    for (int it = 0; it < 8; ++it) {
        const int c = tid + it * 256;
        const int r = c >> 5, o = c & 31;
        short8 v = *(const short8*)(hist16 + (size_t)(m0 + r) * kH + o * 8);
        const int byte = r * 512 + ((o << 4) ^ ((r & 7) << 4));
        *(short8*)((char*)Af + byte) = v;
    }
    __syncthreads();

    #define LAYER(SRC, WW, BIAS, DST)                                           \
    {                                                                           \
        const unsigned short* wb = WW + (size_t)(w * 64 + mrow) * kH + mq * 8;  \
        half8 wall[8][4];                                                       \
        _Pragma("unroll")                                                       \
        for (int kt = 0; kt < 8; ++kt)                                          \
            _Pragma("unroll")                                                   \
            for (int nf = 0; nf < 4; ++nf)                                      \
                wall[kt][nf] = *(const half8*)(wb + nf * 16 * kH + kt * 32);    \
        __builtin_amdgcn_sched_barrier(0);                                      \
        f32x4 acc[4][4];                                                        \
        _Pragma("unroll")                                                       \
        for (int m = 0; m < 4; ++m)                                             \
            _Pragma("unroll")                                                   \
            for (int nf = 0; nf < 4; ++nf) acc[m][nf] = (f32x4){0.f,0.f,0.f,0.f};\
        _Pragma("unroll")                                                       \
        for (int kt = 0; kt < 8; ++kt) {                                        \
            const int k0 = kt * 32;                                             \
            half8 zf[4];                                                        \
            _Pragma("unroll")                                                   \
            for (int m = 0; m < 4; ++m) {                                       \
                const int r = m * 16 + mrow;                                    \
                const int byte = r * 512 + (((k0 + mq * 8) * 2) ^ ((r & 7) << 4)); \
                zf[m] = *(const half8*)((const char*)SRC + byte);               \
            }                                                                   \
            _Pragma("unroll")                                                   \
            for (int m = 0; m < 4; ++m)                                         \
                _Pragma("unroll")                                               \
                for (int nf = 0; nf < 4; ++nf)                                  \
                    acc[m][nf] = __builtin_amdgcn_mfma_f32_16x16x32_f16(        \
                        zf[m], wall[kt][nf], acc[m][nf], 0, 0, 0);              \
        }                                                                       \
        _Pragma("unroll")                                                       \
        for (int m = 0; m < 4; ++m)                                             \
            _Pragma("unroll")                                                   \
            for (int nf = 0; nf < 4; ++nf) {                                    \
                const int col = w * 64 + nf * 16 + mrow;                        \
                const float bv = BIAS[col];                                     \
                _Pragma("unroll")                                               \
                for (int reg = 0; reg < 4; ++reg) {                             \
                    const int lr = m * 16 + mq * 4 + reg;                       \
                    float v = fmaxf(acc[m][nf][reg] + bv, 0.f);                 \
                    const int byte = lr * 512 + (((col >> 3) ^ (lr & 7)) << 4) + (col & 7) * 2; \
                    *(unsigned short*)((char*)DST + byte) = f2h(v);             \
                }                                                               \
            }                                                                   \
        __syncthreads();                                                        \
    }

    LAYER(Af, F1, fc1b, Bf)
    LAYER(Bf, F2, fc2b, Af)

    // fc3: N=64, per wave 1 frag of 16 cols, 4 row tiles
    {
        const int row = w * 16 + mrow;
        const unsigned short* wb = F3 + (size_t)row * kH + mq * 8;
        half8 wall[8];
        #pragma unroll
        for (int kt = 0; kt < 8; ++kt) wall[kt] = *(const half8*)(wb + kt * 32);
        __builtin_amdgcn_sched_barrier(0);
        f32x4 acc[4];
        #pragma unroll
        for (int m = 0; m < 4; ++m) acc[m] = (f32x4){0.f, 0.f, 0.f, 0.f};
        #pragma unroll
        for (int kt = 0; kt < 8; ++kt) {
            const int k0 = kt * 32;
            half8 zf[4];
            #pragma unroll
            for (int m = 0; m < 4; ++m) {
                const int r = m * 16 + mrow;
                const int byte = r * 512 + (((k0 + mq * 8) * 2) ^ ((r & 7) << 4));
                zf[m] = *(const half8*)((const char*)Af + byte);
            }
            #pragma unroll
            for (int m = 0; m < 4; ++m)
                acc[m] = __builtin_amdgcn_mfma_f32_16x16x32_f16(zf[m], wall[kt], acc[m], 0, 0, 0);
        }
        const int col = w * 16 + mrow;
        const float bv = fc3b[col];
        #pragma unroll
        for (int m = 0; m < 4; ++m)
            #pragma unroll
            for (int reg = 0; reg < 4; ++reg) {
                const int grow = m0 + m * 16 + mq * 4 + reg;
                const int t = grow >> 10, bn = grow & 1023, b = bn >> 6, n = bn & 63;
                out[(((size_t)b * kTS + t) * kN + n) * kDout + col] = acc[m][reg] + bv;
            }
    }
    #undef LAYER
}

extern "C" void kernel_launch(void* const* d_in, const int* in_sizes, int n_in,
                              void* d_out, int out_size, void* d_ws, size_t ws_size,
                              hipStream_t stream) {
    const float* inputs    = (const float*)d_in[0];
    const float* rel_rec   = (const float*)d_in[1];
    const float* rel_send  = (const float*)d_in[2];
    const float* rel_types = (const float*)d_in[3];
    const float* W1  = (const float*)d_in[4];  const float* b1  = (const float*)d_in[5];
    const float* W2  = (const float*)d_in[6];  const float* b2  = (const float*)d_in[7];
    const float* Wir = (const float*)d_in[8];  const float* bir = (const float*)d_in[9];
    const float* Whr = (const float*)d_in[10]; const float* bhr = (const float*)d_in[11];
    const float* Wii = (const float*)d_in[12]; const float* bii = (const float*)d_in[13];
    const float* Whi = (const float*)d_in[14]; const float* bhi = (const float*)d_in[15];
    const float* Win = (const float*)d_in[16]; const float* bin_ = (const float*)d_in[17];
    const float* Whn = (const float*)d_in[18]; const float* bhn = (const float*)d_in[19];
    const float* fc1w = (const float*)d_in[20]; const float* fc1b = (const float*)d_in[21];
    const float* fc2w = (const float*)d_in[22]; const float* fc2b = (const float*)d_in[23];
    const float* fc3w = (const float*)d_in[24]; const float* fc3b = (const float*)d_in[25];
    float* out = (float*)d_out;

    char* w = (char*)d_ws;
    auto take = [&](size_t bytes) { char* p = w; w += (bytes + 255) & ~(size_t)255; return p; };
    int* edge_at = (int*)take(kN * kN * 4);
    float* ts = (float*)take(kB * kE * 4);
    unsigned short* W2f = (unsigned short*)take(kH * kH * 2);
    unsigned short* Wri = (unsigned short*)take(512 * 320 * 2);
    unsigned short* Wnh = (unsigned short*)take(kH * kH * 2);
    unsigned short* Wnx = (unsigned short*)take(kH * kDin * 2);
    unsigned short* Wuv = (unsigned short*)take(512 * 256 * 2);
    unsigned short* F1 = (unsigned short*)take(kH * kH * 2);
    unsigned short* F2 = (unsigned short*)take(kH * kH * 2);
    unsigned short* F3 = (unsigned short*)take(kDout * kH * 2);
    float* bri = (float*)take(512 * 4);
    float* Ua = (float*)take((size_t)kBN * kH * 4);
    float* Va = (float*)take((size_t)kBN * kH * 4);
    float* Ub = (float*)take((size_t)kBN * kH * 4);
    float* Vb = (float*)take((size_t)kBN * kH * 4);
    float* ha = (float*)take((size_t)kBN * kH * 4);
    float* hb_ = (float*)take((size_t)kBN * kH * 4);
    unsigned short* hist16 = (unsigned short*)take((size_t)kTS * kBN * kH * 2);

    hipMemsetAsync(edge_at, 0xFF, kN * kN * 4, stream);
    setup_kernel<<<640, 256, 0, stream>>>(
        rel_rec, rel_send, rel_types, W2, Whr, Whi, Whn, Wir, Wii, Win, W1,
        bir, bhr, bii, bhi, fc1w, fc2w, fc3w,
        edge_at, ts, W2f, Wri, Wnh, Wnx, Wuv, F1, F2, F3, bri);
    hipMemsetAsync(Ua, 0, (size_t)kBN * kH * 4, stream);
    hipMemsetAsync(Va, 0, (size_t)kBN * kH * 4, stream);
    hipMemsetAsync(ha, 0, (size_t)kBN * kH * 4, stream);   // h_0 = 0

    float* Uc = Ua; float* Vc = Va; float* Un = Ub; float* Vn = Vb;
    float* hc = ha; float* hn = hb_;
    for (int t = 0; t < kTS; ++t) {
        step_kernel<<<kBN / 4, 512, 0, stream>>>(
            hc, inputs, t, Uc, Vc,
            W2f, b1, b2, ts, edge_at, Wri, Wnh, Wnx, Wuv, bri, bhn, bin_,
            hn, Un, Vn, hist16);
        float* tmp;
        tmp = Uc; Uc = Un; Un = tmp;
        tmp = Vc; Vc = Vn; Vn = tmp;
        tmp = hc; hc = hn; hn = tmp;
    }
    out_kernel<<<kTS * kBN / 64, 256, 0, stream>>>(
        hist16, F1, F2, F3, fc1b, fc2b, fc3b, out);
}